// Round 20
// baseline (460.291 us; speedup 1.0000x reference)
//
#include <hip/hip_runtime.h>

#define IC 4096
typedef unsigned short u16;
typedef unsigned int   u32;
typedef __fp16 h2 __attribute__((ext_vector_type(2)));   // cvt_pkrtz return type

static __device__ __forceinline__ u32 pack_rtz(float a, float b) {
    h2 h = __builtin_amdgcn_cvt_pkrtz(a, b);   // v_cvt_pkrtz_f16_f32
    u32 u; __builtin_memcpy(&u, &h, 4); return u;
}
static __device__ __forceinline__ u32 pack_rne(float a, float b) {
    __fp16 ha = (__fp16)a, hb = (__fp16)b;     // v_cvt_f16_f32 (RNE)
    u16 ua, ub;
    __builtin_memcpy(&ua, &ha, 2);
    __builtin_memcpy(&ub, &hb, 2);
    return (u32)ua | ((u32)ub << 16);
}
static __device__ __forceinline__ float h2lo(u32 r) {
    h2 h; __builtin_memcpy(&h, &r, 4); return (float)h.x;
}
static __device__ __forceinline__ float h2hi(u32 r) {
    h2 h; __builtin_memcpy(&h, &r, 4); return (float)h.y;
}
// v_dot2_f32_f16: 2 fp16 MACs per instruction, fp32 accumulate.
static __device__ __forceinline__ float dot2(u32 a, u32 b, float c) {
    float d;
    asm("v_dot2_f32_f16 %0, %1, %2, %3" : "=v"(d) : "v"(a), "v"(b), "v"(c));
    return d;
}

// Barrier draining only lgkmcnt (r16: proven safe & neutral).
static __device__ __forceinline__ void barrier_lgkm() {
    asm volatile("s_waitcnt lgkmcnt(0)\n\ts_barrier" ::: "memory");
}

// DPP lane permute on the VALU pipe (r18/r19: -25% vs ds_bpermute softmax).
// CTRL: 0xB1 = quad_perm xor1, 0x4E = quad_perm xor2,
// 0x124 = row_ror:4, 0x128 = row_ror:8 (row = 16 lanes).
template<int CTRL>
static __device__ __forceinline__ float dppf(float x) {
    return __int_as_float(__builtin_amdgcn_update_dpp(
        0, __float_as_int(x), CTRL, 0xF, 0xF, true));
}

// one-time fp32 -> fp16(RNE) conversion; thread = one float4 -> 2 u32
__global__ __launch_bounds__(256)
void cvt_fp16(const float* __restrict__ in, u32* __restrict__ out)
{
    const size_t t = (size_t)blockIdx.x * 256 + threadIdx.x;
    const float4 f = ((const float4*)in)[t];
    out[t * 2 + 0] = pack_rne(f.x, f.y);
    out[t * 2 + 1] = pack_rne(f.z, f.w);
}

// ------- primary path: fp16 dot2 + DPP softmax + linear reduce (r19) -------
// r19 established: VALU-busy time is the invariant (~115us/pass); stalls are
// down to 25%. This round halves the u-contraction instruction count with
// v_dot2_f32_f16 on pre-converted fp16 inputs (r15-proven numerics: 1.2e-2).
// Lane map: a = lane&15, dq = lane>>4. part column m holds (a,p) with
// m = (p>>1)*32 + a*2 + (p&1) -- inverted in squash (index math only).
template<int USEV>
__global__ __launch_bounds__(512)
void caps_pass_h(const u32* __restrict__ xh, const u32* __restrict__ wh,
                 const float* __restrict__ vprev, u32* __restrict__ part)
{
    __shared__ float lds[8][4][256];
    const int tid  = threadIdx.x;
    const int wu   = __builtin_amdgcn_readfirstlane(tid >> 6);  // wave 0..7
    const int lane = tid & 63;
    const int a    = lane & 15;   // capsule 0..15  (row-of-16 position)
    const int dq   = lane >> 4;   // d-quad 0..3: lane owns d = dq*4..dq*4+3
    const int ib   = (int)blockIdx.x & 511;   // i-chunk
    const int bh   = (int)blockIdx.x >> 9;    // b-half
    const int i    = ib * 8 + wu;             // this wave's i

    // fp16 W slice: 32 halves = 16 u32 per (a,i,dq); pinned (no remat).
    u32 w[16];
    {
        const u32* wp = wh + ((size_t)a * IC + i) * 64 + dq * 16;
#pragma unroll
        for (int q = 0; q < 4; ++q) {
            const uint4 v4 = *(const uint4*)(wp + q * 4);
            w[q*4+0] = v4.x; w[q*4+1] = v4.y; w[q*4+2] = v4.z; w[q*4+3] = v4.w;
        }
    }
#pragma unroll
    for (int k = 0; k < 16; ++k) asm volatile("" : "+v"(w[k]));

    const int b0 = bh * 128;
    const float SM_SCALE = 4096.0f * 1.44269504088896f;  // logits in log2 units

    for (int ph = 0; ph < 32; ++ph) {
        // prefetch all 4 b's inputs (x is wave-uniform; 4 u32 = 8 halves)
        uint4 xq[4]; float4 va[4];
#pragma unroll
        for (int nb = 0; nb < 4; ++nb) {
            const int b = b0 + ph * 4 + nb;
            xq[nb] = *(const uint4*)(xh + ((size_t)b * IC + i) * 4);
            if (USEV)
                va[nb] = *(const float4*)(vprev + (((size_t)b * 16 + a) * 16 + dq * 4));
        }
#pragma unroll
        for (int nb = 0; nb < 4; ++nb) {
            // u[d] for the lane's 4 d's: 16 dot2 (c-pairs) instead of 32 fma
            float u0 = dot2(xq[nb].x, w[0],  0.0f);
            float u1 = dot2(xq[nb].x, w[4],  0.0f);
            float u2 = dot2(xq[nb].x, w[8],  0.0f);
            float u3 = dot2(xq[nb].x, w[12], 0.0f);
            u0 = dot2(xq[nb].y, w[1],  u0);
            u1 = dot2(xq[nb].y, w[5],  u1);
            u2 = dot2(xq[nb].y, w[9],  u2);
            u3 = dot2(xq[nb].y, w[13], u3);
            u0 = dot2(xq[nb].z, w[2],  u0);
            u1 = dot2(xq[nb].z, w[6],  u1);
            u2 = dot2(xq[nb].z, w[10], u2);
            u3 = dot2(xq[nb].z, w[14], u3);
            u0 = dot2(xq[nb].w, w[3],  u0);
            u1 = dot2(xq[nb].w, w[7],  u1);
            u2 = dot2(xq[nb].w, w[11], u2);
            u3 = dot2(xq[nb].w, w[15], u3);
            float cw;
            if (USEV == 0) {
                cw = 1.0f / 16.0f;
            } else {
                // agree = u . vprev; combine 4 d-quads (the only DS ops left)
                float ag = u0 * va[nb].x + u1 * va[nb].y
                         + u2 * va[nb].z + u3 * va[nb].w;
                ag += __shfl_xor(ag, 16);
                ag += __shfl_xor(ag, 32);
                const float blog2 = SM_SCALE * ag;
                // softmax over the 16-lane row, entirely on VALU DPP
                float m = blog2;
                m = fmaxf(m, dppf<0xB1>(m));    // quad_perm xor1
                m = fmaxf(m, dppf<0x4E>(m));    // quad_perm xor2
                m = fmaxf(m, dppf<0x124>(m));   // row_ror:4
                m = fmaxf(m, dppf<0x128>(m));   // row_ror:8
                const float e = __builtin_amdgcn_exp2f(blog2 - m);
                float sum = e;
                sum += dppf<0xB1>(sum);
                sum += dppf<0x4E>(sum);
                sum += dppf<0x124>(sum);
                sum += dppf<0x128>(sum);
                cw = __fdividef(e, sum);
            }
            // linear per-lane LDS write (b128, conflict-free, r19-proven)
            *(float4*)&lds[wu][nb][lane * 4] =
                make_float4(cw * u0, cw * u1, cw * u2, cw * u3);
        }
        barrier_lgkm();
        // reduce: thread m reads LDS float2 at m*2 (linear, conflict-free)
        // and stores part column m (coalesced); single fp16 RTZ rounding.
        {
            const int nb = tid >> 7;      // 0..3
            const int m  = tid & 127;     // linear float2 / output column
            float s0 = 0.f, s1 = 0.f;
#pragma unroll
            for (int wv = 0; wv < 8; ++wv) {
                const float2 f = *(const float2*)&lds[wv][nb][m * 2];
                s0 += f.x; s1 += f.y;
            }
            part[(size_t)blockIdx.x * 16384 + (size_t)(ph * 4 + nb) * 128 + m] =
                pack_rtz(s0, s1);
        }
        barrier_lgkm();
    }
}

// ---------------- fallback: r19 f32-input path (known-good, 421 us) --------
template<int USEV>
__global__ __launch_bounds__(512)
void caps_pass_part(const float* __restrict__ x, const float* __restrict__ W,
                    const float* __restrict__ vprev, u32* __restrict__ part)
{
    __shared__ float lds[8][4][256];
    const int tid  = threadIdx.x;
    const int wu   = __builtin_amdgcn_readfirstlane(tid >> 6);
    const int lane = tid & 63;
    const int a    = lane & 15;
    const int dq   = lane >> 4;
    const int ib   = (int)blockIdx.x & 511;
    const int bh   = (int)blockIdx.x >> 9;
    const int i    = ib * 8 + wu;

    float w[32];
    {
        const float* wp = W + ((size_t)a * IC + i) * 128 + dq * 32;
#pragma unroll
        for (int q = 0; q < 8; ++q) {
            const float4 f = *(const float4*)(wp + q * 4);
            w[q*4+0] = f.x; w[q*4+1] = f.y; w[q*4+2] = f.z; w[q*4+3] = f.w;
        }
    }
#pragma unroll
    for (int k = 0; k < 32; ++k) asm volatile("" : "+v"(w[k]));

    const int b0 = bh * 128;
    const float SM_SCALE = 4096.0f * 1.44269504088896f;

    for (int ph = 0; ph < 32; ++ph) {
        float4 xa[4], xb[4], va[4];
#pragma unroll
        for (int nb = 0; nb < 4; ++nb) {
            const int b = b0 + ph * 4 + nb;
            const float* xp = x + ((size_t)b * IC + i) * 8;
            xa[nb] = *(const float4*)(xp);
            xb[nb] = *(const float4*)(xp + 4);
            if (USEV)
                va[nb] = *(const float4*)(vprev + (((size_t)b * 16 + a) * 16 + dq * 4));
        }
#pragma unroll
        for (int nb = 0; nb < 4; ++nb) {
            float u0, u1, u2, u3;
            u0 = xa[nb].x * w[0];
            u1 = xa[nb].x * w[8];
            u2 = xa[nb].x * w[16];
            u3 = xa[nb].x * w[24];
            u0 = fmaf(xa[nb].y, w[1],  u0); u1 = fmaf(xa[nb].y, w[9],  u1);
            u2 = fmaf(xa[nb].y, w[17], u2); u3 = fmaf(xa[nb].y, w[25], u3);
            u0 = fmaf(xa[nb].z, w[2],  u0); u1 = fmaf(xa[nb].z, w[10], u1);
            u2 = fmaf(xa[nb].z, w[18], u2); u3 = fmaf(xa[nb].z, w[26], u3);
            u0 = fmaf(xa[nb].w, w[3],  u0); u1 = fmaf(xa[nb].w, w[11], u1);
            u2 = fmaf(xa[nb].w, w[19], u2); u3 = fmaf(xa[nb].w, w[27], u3);
            u0 = fmaf(xb[nb].x, w[4],  u0); u1 = fmaf(xb[nb].x, w[12], u1);
            u2 = fmaf(xb[nb].x, w[20], u2); u3 = fmaf(xb[nb].x, w[28], u3);
            u0 = fmaf(xb[nb].y, w[5],  u0); u1 = fmaf(xb[nb].y, w[13], u1);
            u2 = fmaf(xb[nb].y, w[21], u2); u3 = fmaf(xb[nb].y, w[29], u3);
            u0 = fmaf(xb[nb].z, w[6],  u0); u1 = fmaf(xb[nb].z, w[14], u1);
            u2 = fmaf(xb[nb].z, w[22], u2); u3 = fmaf(xb[nb].z, w[30], u3);
            u0 = fmaf(xb[nb].w, w[7],  u0); u1 = fmaf(xb[nb].w, w[15], u1);
            u2 = fmaf(xb[nb].w, w[23], u2); u3 = fmaf(xb[nb].w, w[31], u3);
            float cw;
            if (USEV == 0) {
                cw = 1.0f / 16.0f;
            } else {
                float ag = u0 * va[nb].x + u1 * va[nb].y
                         + u2 * va[nb].z + u3 * va[nb].w;
                ag += __shfl_xor(ag, 16);
                ag += __shfl_xor(ag, 32);
                const float blog2 = SM_SCALE * ag;
                float m = blog2;
                m = fmaxf(m, dppf<0xB1>(m));
                m = fmaxf(m, dppf<0x4E>(m));
                m = fmaxf(m, dppf<0x124>(m));
                m = fmaxf(m, dppf<0x128>(m));
                const float e = __builtin_amdgcn_exp2f(blog2 - m);
                float sum = e;
                sum += dppf<0xB1>(sum);
                sum += dppf<0x4E>(sum);
                sum += dppf<0x124>(sum);
                sum += dppf<0x128>(sum);
                cw = __fdividef(e, sum);
            }
            *(float4*)&lds[wu][nb][lane * 4] =
                make_float4(cw * u0, cw * u1, cw * u2, cw * u3);
        }
        barrier_lgkm();
        {
            const int nb = tid >> 7;
            const int m  = tid & 127;
            float s0 = 0.f, s1 = 0.f;
#pragma unroll
            for (int wv = 0; wv < 8; ++wv) {
                const float2 f = *(const float2*)&lds[wv][nb][m * 2];
                s0 += f.x; s1 += f.y;
            }
            part[(size_t)blockIdx.x * 16384 + (size_t)(ph * 4 + nb) * 128 + m] =
                pack_rtz(s0, s1);
        }
        barrier_lgkm();
    }
}

// Fused 512-deep partial reduction + squash. Thread = (b, r = a*8 + dpair):
// inverts the (a,p)->m layout permutation in index math only.
template<int ADDP>
__global__ __launch_bounds__(256)
void caps_squash_part(const u32* __restrict__ part, float* __restrict__ vout,
                      const float* __restrict__ vprev)
{
    const int gt = (int)blockIdx.x * 256 + (int)threadIdx.x;  // 0..32767
    const int b  = gt >> 7;
    const int r  = gt & 127;                                  // a*8 + dpair
    const int a  = r >> 3;
    const int p  = r & 7;
    const int m  = (p >> 1) * 32 + a * 2 + (p & 1);           // part column
    const int h  = b >> 7;                                    // b-half
    const int lb = b & 127;                                   // local b in tile
    const u32* pp = part + ((size_t)h * 512) * 16384 + (size_t)lb * 128 + m;
    float f0 = 0.f, f1 = 0.f;
#pragma unroll 8
    for (int ic = 0; ic < 512; ++ic) {
        const u32 raw = pp[(size_t)ic * 16384];
        f0 += h2lo(raw);
        f1 += h2hi(raw);
    }
    float sq = f0 * f0 + f1 * f1;
    sq += __shfl_xor(sq, 1);
    sq += __shfl_xor(sq, 2);
    sq += __shfl_xor(sq, 4);
    const float scale = sq / ((1.0f + sq) * sqrtf(sq + 1e-7f));
    float o0 = f0 * scale, o1 = f1 * scale;
    if (ADDP) {
        const float2 pv = *(const float2*)(vprev + (size_t)b * 256 + r * 2);
        o0 += pv.x; o1 += pv.y;
    }
    *(float2*)(vout + (size_t)b * 256 + r * 2) = make_float2(o0, o1);
}

extern "C" void kernel_launch(void* const* d_in, const int* in_sizes, int n_in,
                              void* d_out, int out_size, void* d_ws, size_t ws_size,
                              hipStream_t stream)
{
    const float* x = (const float*)d_in[0];   // [256, 4096, 8]
    const float* W = (const float*)d_in[1];   // [16, 4096, 16, 8]
    float* out = (float*)d_out;               // [256, 16, 16]

    const size_t part_b = (size_t)1024 * 16384 * 4;     // 64 MiB fp16 partials
    const size_t vv_b   = (size_t)2 * 65536 * 4;        // v1 + vs
    const size_t half_b = (size_t)8388608 * 2;          // 16 MiB per fp16 input
    const size_t need_h   = part_b + vv_b + 2 * half_b; // ~96.5 MiB
    const size_t need_f32 = part_b + vv_b;              // ~64.5 MiB

    if (ws_size >= need_h) {
        u32*  part = (u32*)d_ws;
        float* v1  = (float*)((char*)d_ws + part_b);
        float* vs  = v1 + 65536;
        u32*  xh   = (u32*)((char*)d_ws + part_b + vv_b);
        u32*  wh   = xh + 4194304;
        cvt_fp16<<<8192, 256, 0, stream>>>(x, xh);
        cvt_fp16<<<8192, 256, 0, stream>>>(W, wh);
        caps_pass_h<0><<<1024, 512, 0, stream>>>(xh, wh, nullptr, part);
        caps_squash_part<0><<<128, 256, 0, stream>>>(part, v1, nullptr);
        caps_pass_h<1><<<1024, 512, 0, stream>>>(xh, wh, v1, part);
        caps_squash_part<1><<<128, 256, 0, stream>>>(part, vs, v1);
        caps_pass_h<1><<<1024, 512, 0, stream>>>(xh, wh, vs, part);
        caps_squash_part<0><<<128, 256, 0, stream>>>(part, out, nullptr);
    } else if (ws_size >= need_f32) {
        u32*  part = (u32*)d_ws;
        float* v1  = (float*)((char*)d_ws + part_b);
        float* vs  = v1 + 65536;
        caps_pass_part<0><<<1024, 512, 0, stream>>>(x, W, nullptr, part);
        caps_squash_part<0><<<128, 256, 0, stream>>>(part, v1, nullptr);
        caps_pass_part<1><<<1024, 512, 0, stream>>>(x, W, v1, part);
        caps_squash_part<1><<<128, 256, 0, stream>>>(part, vs, v1);
        caps_pass_part<1><<<1024, 512, 0, stream>>>(x, W, vs, part);
        caps_squash_part<0><<<128, 256, 0, stream>>>(part, out, nullptr);
    }
}

// Round 21
// 421.957 us; speedup vs baseline: 1.0908x; 1.0908x over previous
//
#include <hip/hip_runtime.h>

#define IC 4096
typedef unsigned short u16;
typedef unsigned int   u32;
typedef __fp16 h2 __attribute__((ext_vector_type(2)));   // cvt_pkrtz return type

static __device__ __forceinline__ u32 pack_rtz(float a, float b) {
    h2 h = __builtin_amdgcn_cvt_pkrtz(a, b);   // v_cvt_pkrtz_f16_f32
    u32 u; __builtin_memcpy(&u, &h, 4); return u;
}
static __device__ __forceinline__ float h2lo(u32 r) {
    h2 h; __builtin_memcpy(&h, &r, 4); return (float)h.x;
}
static __device__ __forceinline__ float h2hi(u32 r) {
    h2 h; __builtin_memcpy(&h, &r, 4); return (float)h.y;
}

// Barrier draining only lgkmcnt (r16: proven safe & neutral).
static __device__ __forceinline__ void barrier_lgkm() {
    asm volatile("s_waitcnt lgkmcnt(0)\n\ts_barrier" ::: "memory");
}

// DPP lane permute on the VALU pipe (r18/r19: -25% vs ds_bpermute softmax).
// CTRL: 0xB1 = quad_perm xor1, 0x4E = quad_perm xor2,
// 0x124 = row_ror:4, 0x128 = row_ror:8 (row = 16 lanes).
template<int CTRL>
static __device__ __forceinline__ float dppf(float x) {
    return __int_as_float(__builtin_amdgcn_update_dpp(
        0, __float_as_int(x), CTRL, 0xF, 0xF, true));
}

// ---------------- primary path: r19 champion + hoisted va addressing -------
// r20 post-mortem: dot2/fp16 inputs REGRESSED (VALU time 115->127us) --
// scalar f32 fma is the fastest contraction on this chip. This round is r19
// verbatim plus one micro-opt: the per-lane va offset (a*16+dq*4) is hoisted
// out of all loops, so each phase's 4 va loads are base + nb*256 (immediate
// offsets, no per-load VALU address math).
// Lane map: a = lane&15, dq = lane>>4. part column m holds (a,p) with
// m = (p>>1)*32 + a*2 + (p&1) -- inverted in squash (index math only).
template<int USEV>
__global__ __launch_bounds__(512)
void caps_pass_part(const float* __restrict__ x, const float* __restrict__ W,
                    const float* __restrict__ vprev, u32* __restrict__ part)
{
    __shared__ float lds[8][4][256];
    const int tid  = threadIdx.x;
    const int wu   = __builtin_amdgcn_readfirstlane(tid >> 6);  // wave 0..7
    const int lane = tid & 63;
    const int a    = lane & 15;   // capsule 0..15  (row-of-16 position)
    const int dq   = lane >> 4;   // d-quad 0..3: lane owns d = dq*4..dq*4+3
    const int ib   = (int)blockIdx.x & 511;   // i-chunk
    const int bh   = (int)blockIdx.x >> 9;    // b-half
    const int i    = ib * 8 + wu;             // this wave's i

    float w[32];
    {
        const float* wp = W + ((size_t)a * IC + i) * 128 + dq * 32;
#pragma unroll
        for (int q = 0; q < 8; ++q) {
            const float4 f = *(const float4*)(wp + q * 4);
            w[q*4+0] = f.x; w[q*4+1] = f.y; w[q*4+2] = f.z; w[q*4+3] = f.w;
        }
    }
#pragma unroll
    for (int k = 0; k < 32; ++k) asm volatile("" : "+v"(w[k]));  // no remat

    const int b0 = bh * 128;
    const float SM_SCALE = 4096.0f * 1.44269504088896f;  // logits in log2 units
    // per-lane va offset, loop-invariant (hoisted: saves per-load VALU math)
    const float* vbase = USEV ? (vprev + (size_t)b0 * 256 + a * 16 + dq * 4)
                              : nullptr;

    for (int ph = 0; ph < 32; ++ph) {
        // prefetch all 4 b's inputs (x is wave-uniform -> scalar loads;
        // va loads are vbase + const offsets -> immediate-offset form)
        float4 xa[4], xb[4], va[4];
        const float* xp0 = x + ((size_t)(b0 + ph * 4) * IC + i) * 8;
#pragma unroll
        for (int nb = 0; nb < 4; ++nb) {
            const float* xp = xp0 + (size_t)nb * IC * 8;
            xa[nb] = *(const float4*)(xp);
            xb[nb] = *(const float4*)(xp + 4);
            if (USEV)
                va[nb] = *(const float4*)(vbase + (size_t)(ph * 4 + nb) * 256);
        }
#pragma unroll
        for (int nb = 0; nb < 4; ++nb) {
            float u0, u1, u2, u3;
            u0 = xa[nb].x * w[0];
            u1 = xa[nb].x * w[8];
            u2 = xa[nb].x * w[16];
            u3 = xa[nb].x * w[24];
            u0 = fmaf(xa[nb].y, w[1],  u0); u1 = fmaf(xa[nb].y, w[9],  u1);
            u2 = fmaf(xa[nb].y, w[17], u2); u3 = fmaf(xa[nb].y, w[25], u3);
            u0 = fmaf(xa[nb].z, w[2],  u0); u1 = fmaf(xa[nb].z, w[10], u1);
            u2 = fmaf(xa[nb].z, w[18], u2); u3 = fmaf(xa[nb].z, w[26], u3);
            u0 = fmaf(xa[nb].w, w[3],  u0); u1 = fmaf(xa[nb].w, w[11], u1);
            u2 = fmaf(xa[nb].w, w[19], u2); u3 = fmaf(xa[nb].w, w[27], u3);
            u0 = fmaf(xb[nb].x, w[4],  u0); u1 = fmaf(xb[nb].x, w[12], u1);
            u2 = fmaf(xb[nb].x, w[20], u2); u3 = fmaf(xb[nb].x, w[28], u3);
            u0 = fmaf(xb[nb].y, w[5],  u0); u1 = fmaf(xb[nb].y, w[13], u1);
            u2 = fmaf(xb[nb].y, w[21], u2); u3 = fmaf(xb[nb].y, w[29], u3);
            u0 = fmaf(xb[nb].z, w[6],  u0); u1 = fmaf(xb[nb].z, w[14], u1);
            u2 = fmaf(xb[nb].z, w[22], u2); u3 = fmaf(xb[nb].z, w[30], u3);
            u0 = fmaf(xb[nb].w, w[7],  u0); u1 = fmaf(xb[nb].w, w[15], u1);
            u2 = fmaf(xb[nb].w, w[23], u2); u3 = fmaf(xb[nb].w, w[31], u3);
            float cw;
            if (USEV == 0) {
                cw = 1.0f / 16.0f;
            } else {
                // agree = u . vprev; combine the 4 d-quads (lanes a, a+16,
                // a+32, a+48) -- the only remaining DS ops (2 vs 10).
                float ag = u0 * va[nb].x + u1 * va[nb].y
                         + u2 * va[nb].z + u3 * va[nb].w;
                ag += __shfl_xor(ag, 16);
                ag += __shfl_xor(ag, 32);
                const float blog2 = SM_SCALE * ag;
                // softmax over the 16-lane row, entirely on VALU DPP
                float m = blog2;
                m = fmaxf(m, dppf<0xB1>(m));    // quad_perm xor1
                m = fmaxf(m, dppf<0x4E>(m));    // quad_perm xor2
                m = fmaxf(m, dppf<0x124>(m));   // row_ror:4
                m = fmaxf(m, dppf<0x128>(m));   // row_ror:8
                const float e = __builtin_amdgcn_exp2f(blog2 - m);
                float sum = e;
                sum += dppf<0xB1>(sum);
                sum += dppf<0x4E>(sum);
                sum += dppf<0x124>(sum);
                sum += dppf<0x128>(sum);
                cw = __fdividef(e, sum);
            }
            // linear per-lane LDS write (b128, conflict-free, r19-proven);
            // element order: float index = dq*64 + a*4 + j.
            *(float4*)&lds[wu][nb][lane * 4] =
                make_float4(cw * u0, cw * u1, cw * u2, cw * u3);
        }
        barrier_lgkm();
        // reduce: thread m = tid&127 reads LDS float2 at m*2 (LINEAR ->
        // conflict-free) and stores part column m (coalesced); single fp16
        // RTZ rounding at the store.
        {
            const int nb = tid >> 7;      // 0..3
            const int m  = tid & 127;     // linear float2 / output column
            float s0 = 0.f, s1 = 0.f;
#pragma unroll
            for (int wv = 0; wv < 8; ++wv) {
                const float2 f = *(const float2*)&lds[wv][nb][m * 2];
                s0 += f.x; s1 += f.y;
            }
            part[(size_t)blockIdx.x * 16384 + (size_t)(ph * 4 + nb) * 128 + m] =
                pack_rtz(s0, s1);
        }
        barrier_lgkm();
    }
}

// Fused 512-deep partial reduction + squash. Thread = (b, r = a*8 + dpair):
// inverts the (a,p)->m layout permutation in index math only.
template<int ADDP>
__global__ __launch_bounds__(256)
void caps_squash_part(const u32* __restrict__ part, float* __restrict__ vout,
                      const float* __restrict__ vprev)
{
    const int gt = (int)blockIdx.x * 256 + (int)threadIdx.x;  // 0..32767
    const int b  = gt >> 7;
    const int r  = gt & 127;                                  // a*8 + dpair
    const int a  = r >> 3;
    const int p  = r & 7;
    const int m  = (p >> 1) * 32 + a * 2 + (p & 1);           // part column
    const int h  = b >> 7;                                    // b-half
    const int lb = b & 127;                                   // local b in tile
    const u32* pp = part + ((size_t)h * 512) * 16384 + (size_t)lb * 128 + m;
    float f0 = 0.f, f1 = 0.f;
#pragma unroll 8
    for (int ic = 0; ic < 512; ++ic) {
        const u32 raw = pp[(size_t)ic * 16384];
        f0 += h2lo(raw);
        f1 += h2hi(raw);
    }
    float sq = f0 * f0 + f1 * f1;
    sq += __shfl_xor(sq, 1);
    sq += __shfl_xor(sq, 2);
    sq += __shfl_xor(sq, 4);
    const float scale = sq / ((1.0f + sq) * sqrtf(sq + 1e-7f));
    float o0 = f0 * scale, o1 = f1 * scale;
    if (ADDP) {
        const float2 pv = *(const float2*)(vprev + (size_t)b * 256 + r * 2);
        o0 += pv.x; o1 += pv.y;
    }
    *(float2*)(vout + (size_t)b * 256 + r * 2) = make_float2(o0, o1);
}

// ---------------- legacy fallback (round-4, known-good) ----------------
template<int USEV>
__global__ __launch_bounds__(512)
void legacy_pass(const float* __restrict__ x, const float* __restrict__ W,
                 const float* __restrict__ vprev, float* __restrict__ s_rep,
                 int n_rep)
{
    __shared__ float lds[8][4][256];
    const int tid  = threadIdx.x;
    const int wu   = __builtin_amdgcn_readfirstlane(tid >> 6);
    const int lane = tid & 63;
    const int a    = lane >> 2;
    const int dq   = lane & 3;
    const int ichunk = (int)blockIdx.x >> 1;
    const int bhalf  = (int)blockIdx.x & 1;
    const int i0 = ichunk * 32 + wu * 4;
    const int rep = (int)blockIdx.x & (n_rep - 1);
    float* srep = s_rep + (size_t)rep * 65536;

    float w[4][32];
#pragma unroll
    for (int ii = 0; ii < 4; ++ii) {
        const float* wp = W + ((size_t)a * IC + (size_t)(i0 + ii)) * 128 + dq * 32;
#pragma unroll
        for (int q = 0; q < 8; ++q) {
            const float4 f = *(const float4*)(wp + q * 4);
            w[ii][q*4+0]=f.x; w[ii][q*4+1]=f.y; w[ii][q*4+2]=f.z; w[ii][q*4+3]=f.w;
        }
    }
#pragma unroll
    for (int ii = 0; ii < 4; ++ii)
#pragma unroll
        for (int k = 0; k < 32; ++k) asm volatile("" : "+v"(w[ii][k]));

    const int b0 = bhalf * 128;
    for (int ph = 0; ph < 32; ++ph) {
        float sl[4][4];
#pragma unroll
        for (int nb = 0; nb < 4; ++nb) {
            sl[nb][0]=0.f; sl[nb][1]=0.f; sl[nb][2]=0.f; sl[nb][3]=0.f;
            const int b = b0 + ph * 4 + nb;
            float4 va;
            if (USEV)
                va = *(const float4*)(vprev + (((size_t)b * 16 + a) * 16 + dq * 4));
#pragma unroll
            for (int ii = 0; ii < 4; ++ii) {
                const float* xp = x + ((size_t)b * IC + (size_t)(i0 + ii)) * 8;
                const float4 xa = *(const float4*)(xp);
                const float4 xb = *(const float4*)(xp + 4);
                float u0, u1, u2, u3;
                u0 = xa.x * w[ii][0];  u1 = xa.x * w[ii][8];
                u2 = xa.x * w[ii][16]; u3 = xa.x * w[ii][24];
                u0 = fmaf(xa.y, w[ii][1],  u0); u1 = fmaf(xa.y, w[ii][9],  u1);
                u2 = fmaf(xa.y, w[ii][17], u2); u3 = fmaf(xa.y, w[ii][25], u3);
                u0 = fmaf(xa.z, w[ii][2],  u0); u1 = fmaf(xa.z, w[ii][10], u1);
                u2 = fmaf(xa.z, w[ii][18], u2); u3 = fmaf(xa.z, w[ii][26], u3);
                u0 = fmaf(xa.w, w[ii][3],  u0); u1 = fmaf(xa.w, w[ii][11], u1);
                u2 = fmaf(xa.w, w[ii][19], u2); u3 = fmaf(xa.w, w[ii][27], u3);
                u0 = fmaf(xb.x, w[ii][4],  u0); u1 = fmaf(xb.x, w[ii][12], u1);
                u2 = fmaf(xb.x, w[ii][20], u2); u3 = fmaf(xb.x, w[ii][28], u3);
                u0 = fmaf(xb.y, w[ii][5],  u0); u1 = fmaf(xb.y, w[ii][13], u1);
                u2 = fmaf(xb.y, w[ii][21], u2); u3 = fmaf(xb.y, w[ii][29], u3);
                u0 = fmaf(xb.z, w[ii][6],  u0); u1 = fmaf(xb.z, w[ii][14], u1);
                u2 = fmaf(xb.z, w[ii][22], u2); u3 = fmaf(xb.z, w[ii][30], u3);
                u0 = fmaf(xb.w, w[ii][7],  u0); u1 = fmaf(xb.w, w[ii][15], u1);
                u2 = fmaf(xb.w, w[ii][23], u2); u3 = fmaf(xb.w, w[ii][31], u3);
                float cw;
                if (USEV == 0) {
                    cw = 1.0f / 16.0f;
                } else {
                    float ag = u0*va.x + u1*va.y + u2*va.z + u3*va.w;
                    ag += __shfl_xor(ag, 1);
                    ag += __shfl_xor(ag, 2);
                    const float blog = 4096.0f * ag;
                    float m = blog;
                    m = fmaxf(m, __shfl_xor(m, 4));
                    m = fmaxf(m, __shfl_xor(m, 8));
                    m = fmaxf(m, __shfl_xor(m, 16));
                    m = fmaxf(m, __shfl_xor(m, 32));
                    const float e = __expf(blog - m);
                    float sum = e;
                    sum += __shfl_xor(sum, 4);
                    sum += __shfl_xor(sum, 8);
                    sum += __shfl_xor(sum, 16);
                    sum += __shfl_xor(sum, 32);
                    cw = __fdividef(e, sum);
                }
                sl[nb][0] = fmaf(cw, u0, sl[nb][0]);
                sl[nb][1] = fmaf(cw, u1, sl[nb][1]);
                sl[nb][2] = fmaf(cw, u2, sl[nb][2]);
                sl[nb][3] = fmaf(cw, u3, sl[nb][3]);
            }
        }
#pragma unroll
        for (int nb = 0; nb < 4; ++nb)
            *(float4*)&lds[wu][nb][lane * 4] =
                make_float4(sl[nb][0], sl[nb][1], sl[nb][2], sl[nb][3]);
        __syncthreads();
        if (tid < 256) {
            const int bsel = tid >> 6;
            const int ad4  = (tid & 63) * 4;
            float4 acc = make_float4(0.f, 0.f, 0.f, 0.f);
#pragma unroll
            for (int wv = 0; wv < 8; ++wv) {
                const float4 f = *(const float4*)&lds[wv][bsel][ad4];
                acc.x += f.x; acc.y += f.y; acc.z += f.z; acc.w += f.w;
            }
            float* dst = srep + (size_t)(b0 + ph * 4 + bsel) * 256 + ad4;
            unsafeAtomicAdd(dst + 0, acc.x);
            unsafeAtomicAdd(dst + 1, acc.y);
            unsafeAtomicAdd(dst + 2, acc.z);
            unsafeAtomicAdd(dst + 3, acc.w);
        }
        __syncthreads();
    }
}

template<int ADDP, int ZERO>
__global__ void legacy_squash(float* __restrict__ srep, int n_rep,
                              float* __restrict__ vout, const float* __restrict__ vprev)
{
    const int t = (int)blockIdx.x * 256 + (int)threadIdx.x;
    float4 f0 = make_float4(0.f,0.f,0.f,0.f), f1 = f0, f2 = f0, f3 = f0;
    for (int r = 0; r < n_rep; ++r) {
        float* sp = srep + (size_t)r * 65536 + (size_t)t * 16;
        const float4 a0 = *(const float4*)(sp + 0);
        const float4 a1 = *(const float4*)(sp + 4);
        const float4 a2 = *(const float4*)(sp + 8);
        const float4 a3 = *(const float4*)(sp + 12);
        f0.x+=a0.x; f0.y+=a0.y; f0.z+=a0.z; f0.w+=a0.w;
        f1.x+=a1.x; f1.y+=a1.y; f1.z+=a1.z; f1.w+=a1.w;
        f2.x+=a2.x; f2.y+=a2.y; f2.z+=a2.z; f2.w+=a2.w;
        f3.x+=a3.x; f3.y+=a3.y; f3.z+=a3.z; f3.w+=a3.w;
        if (ZERO) {
            const float4 z = make_float4(0.f,0.f,0.f,0.f);
            *(float4*)(sp+0)=z; *(float4*)(sp+4)=z; *(float4*)(sp+8)=z; *(float4*)(sp+12)=z;
        }
    }
    float sq = f0.x*f0.x+f0.y*f0.y+f0.z*f0.z+f0.w*f0.w
             + f1.x*f1.x+f1.y*f1.y+f1.z*f1.z+f1.w*f1.w
             + f2.x*f2.x+f2.y*f2.y+f2.z*f2.z+f2.w*f2.w
             + f3.x*f3.x+f3.y*f3.y+f3.z*f3.z+f3.w*f3.w;
    const float scale = sq / ((1.0f + sq) * sqrtf(sq + 1e-7f));
    float4 o0, o1, o2, o3;
    o0.x=f0.x*scale; o0.y=f0.y*scale; o0.z=f0.z*scale; o0.w=f0.w*scale;
    o1.x=f1.x*scale; o1.y=f1.y*scale; o1.z=f1.z*scale; o1.w=f1.w*scale;
    o2.x=f2.x*scale; o2.y=f2.y*scale; o2.z=f2.z*scale; o2.w=f2.w*scale;
    o3.x=f3.x*scale; o3.y=f3.y*scale; o3.z=f3.z*scale; o3.w=f3.w*scale;
    if (ADDP) {
        const float* pp = vprev + (size_t)t * 16;
        const float4 p0 = *(const float4*)(pp + 0);
        const float4 p1 = *(const float4*)(pp + 4);
        const float4 p2 = *(const float4*)(pp + 8);
        const float4 p3 = *(const float4*)(pp + 12);
        o0.x+=p0.x; o0.y+=p0.y; o0.z+=p0.z; o0.w+=p0.w;
        o1.x+=p1.x; o1.y+=p1.y; o1.z+=p1.z; o1.w+=p1.w;
        o2.x+=p2.x; o2.y+=p2.y; o2.z+=p2.z; o2.w+=p2.w;
        o3.x+=p3.x; o3.y+=p3.y; o3.z+=p3.z; o3.w+=p3.w;
    }
    float* vp = vout + (size_t)t * 16;
    *(float4*)(vp+0)=o0; *(float4*)(vp+4)=o1; *(float4*)(vp+8)=o2; *(float4*)(vp+12)=o3;
}

__global__ void legacy_zero(float* __restrict__ p)
{
    *(float4*)(p + ((size_t)blockIdx.x * 256 + threadIdx.x) * 4) =
        make_float4(0.f, 0.f, 0.f, 0.f);
}

extern "C" void kernel_launch(void* const* d_in, const int* in_sizes, int n_in,
                              void* d_out, int out_size, void* d_ws, size_t ws_size,
                              hipStream_t stream)
{
    const float* x = (const float*)d_in[0];   // [256, 4096, 8]
    const float* W = (const float*)d_in[1];   // [16, 4096, 16, 8]
    float* out = (float*)d_out;               // [256, 16, 16]

    // fp16 partials: 1024 tiles x 16384 u32 = 64 MiB
    const size_t need16 = (size_t)1024 * 16384 * 4 + 2 * 65536 * 4;

    if (ws_size >= need16) {
        u32*  part = (u32*)d_ws;
        float* v1  = (float*)((char*)d_ws + (size_t)1024 * 16384 * 4);
        float* vs  = v1 + 65536;
        caps_pass_part<0><<<1024, 512, 0, stream>>>(x, W, nullptr, part);
        caps_squash_part<0><<<128, 256, 0, stream>>>(part, v1, nullptr);
        caps_pass_part<1><<<1024, 512, 0, stream>>>(x, W, v1, part);
        caps_squash_part<1><<<128, 256, 0, stream>>>(part, vs, v1);
        caps_pass_part<1><<<1024, 512, 0, stream>>>(x, W, vs, part);
        caps_squash_part<0><<<128, 256, 0, stream>>>(part, out, nullptr);
    } else {
        int R = 1;
        if (ws_size >= (size_t)(8 + 2) * 65536 * 4) R = 8;
        else if (ws_size >= (size_t)(2 + 2) * 65536 * 4) R = 2;
        float* srep = (float*)d_ws;
        float* v1   = srep + (size_t)R * 65536;
        float* vs   = v1 + 65536;
        legacy_zero<<<R * 64, 256, 0, stream>>>(srep);
        legacy_pass<0><<<256, 512, 0, stream>>>(x, W, nullptr, srep, R);
        legacy_squash<0, 1><<<16, 256, 0, stream>>>(srep, R, v1, nullptr);
        legacy_pass<1><<<256, 512, 0, stream>>>(x, W, v1, srep, R);
        legacy_squash<1, 1><<<16, 256, 0, stream>>>(srep, R, vs, v1);
        legacy_pass<1><<<256, 512, 0, stream>>>(x, W, vs, srep, R);
        legacy_squash<0, 0><<<16, 256, 0, stream>>>(srep, R, out, nullptr);
    }
}